// Round 11
// baseline (523.852 us; speedup 1.0000x reference)
//
#include <hip/hip_runtime.h>
#include <math.h>

#define MAXNB 1024     // max buckets (N <= 262144 with 256 nodes/bucket)
#define BCH_CNT 2048   // edges per block in count kernel
#define BCH_BIND 4096  // edges per block in dst-bin kernel (512 threads)
#define BCAP  16384    // per-bucket edge capacity in finalize (mean 4096)

typedef __attribute__((ext_vector_type(8))) __bf16 bf16x8;
typedef __attribute__((ext_vector_type(4))) float floatx4;

__device__ inline bf16x8 asbf(uint4 u) {
  union { uint4 u; bf16x8 b; } c; c.u = u; return c.b;
}

// ---------- bf16 helpers ----------
__device__ inline unsigned short f2bf(float f) {
  union { float f; unsigned u; } v; v.f = f;
  unsigned r = v.u + 0x7fffu + ((v.u >> 16) & 1u);   // round-to-nearest-even
  return (unsigned short)(r >> 16);
}
__device__ inline float bf2f(unsigned short u) {
  union { unsigned u; float f; } v; v.u = ((unsigned)u) << 16;
  return v.f;
}
__device__ inline float2 bfp2f2(unsigned u) {       // packed bf16x2 -> float2
  union { unsigned u; float f; } a, b;
  a.u = u << 16;
  b.u = u & 0xffff0000u;
  float2 r; r.x = a.f; r.y = b.f; return r;
}
// split v into hi=bf16(v), lo=bf16(v-hi); packed pair for 2 values
__device__ inline void hilo2(float v0, float v1, unsigned& h, unsigned& l) {
  unsigned short h0 = f2bf(v0); float r0 = v0 - bf2f(h0);
  unsigned short h1 = f2bf(v1); float r1 = v1 - bf2f(h1);
  h = (unsigned)h0 | ((unsigned)h1 << 16);
  l = (unsigned)f2bf(r0) | ((unsigned)f2bf(r1) << 16);
}

// ---------------- CSR build ----------------
// count: dst bucket histogram (for the bin pass) + DIRECT global out-degree
// atomics (replaces the entire src-side binning: deg is N ints, L2-resident,
// ~16 collisions/address).
__global__ __launch_bounds__(256) void count_deg_kernel(
    const int* __restrict__ src, const int* __restrict__ dst,
    int* __restrict__ bcnt, int* __restrict__ deg, int E, int NB) {
  __shared__ int histd[MAXNB];
  int tid = threadIdx.x;
  for (int i = tid; i < MAXNB; i += 256) histd[i] = 0;
  __syncthreads();
  int e0 = blockIdx.x * BCH_CNT;
  #pragma unroll
  for (int k = 0; k < BCH_CNT/256; ++k) {
    int e = e0 + k*256 + tid;
    if (e < E) {
      atomicAdd(&histd[dst[e] >> 8], 1);
      atomicAdd(&deg[src[e]], 1);
    }
  }
  __syncthreads();
  for (int i = tid; i < NB; i += 256)
    if (histd[i]) atomicAdd(&bcnt[i], histd[i]);
}

// single-pass scan of dst bucket counts -> bbase/bcur, rp[N]=E
__global__ __launch_bounds__(256) void scan1_kernel(
    const int* __restrict__ bcnt, int* __restrict__ bbase, int* __restrict__ bcur,
    int* __restrict__ rp, int NB, int N, int E) {
  __shared__ int sh[256];
  int t = threadIdx.x;
  int base = t * 4;
  int v0 = (base+0 < NB) ? bcnt[base+0] : 0;
  int v1 = (base+1 < NB) ? bcnt[base+1] : 0;
  int v2 = (base+2 < NB) ? bcnt[base+2] : 0;
  int v3 = (base+3 < NB) ? bcnt[base+3] : 0;
  int s = v0+v1+v2+v3;
  sh[t] = s;
  __syncthreads();
  for (int off=1; off<256; off<<=1){
    int x = (t >= off) ? sh[t-off] : 0;
    __syncthreads();
    sh[t] += x;
    __syncthreads();
  }
  int run = sh[t] - s;
  if (base+0 <= NB) { bbase[base+0] = run; if (base+0 < NB) bcur[base+0] = run; } run += v0;
  if (base+1 <= NB) { bbase[base+1] = run; if (base+1 < NB) bcur[base+1] = run; } run += v1;
  if (base+2 <= NB) { bbase[base+2] = run; if (base+2 < NB) bcur[base+2] = run; } run += v2;
  if (base+3 <= NB) { bbase[base+3] = run; if (base+3 < NB) bcur[base+3] = run; }
  if (t == 0) rp[N] = E;
}

// bin by dst bucket. 512 threads / 4096 edges per block (runs ~10.5 edges/bucket
// -> coalesced writeback). Bucket id recorded in LDS ushort at scatter time --
// NO binary search in the writeback (the 10-iteration LDS search chain was the
// dominant serial cost of the old kernel: 67us @ 0.5 TB/s).
__global__ __launch_bounds__(512) void bin_dst_kernel(
    const int* __restrict__ src, const int* __restrict__ dst,
    int* __restrict__ bcur, unsigned* __restrict__ ebuf, int E, int NB) {
  __shared__ int hist[MAXNB];
  __shared__ int scanb[MAXNB];
  __shared__ int rbase[MAXNB];
  __shared__ int lcur[MAXNB];
  __shared__ int tmp[512];
  __shared__ unsigned stage[BCH_BIND];
  __shared__ unsigned short bkt[BCH_BIND];
  int tid = threadIdx.x;
  int e0 = blockIdx.x * BCH_BIND;
  int nedge = E - e0; if (nedge > BCH_BIND) nedge = BCH_BIND; if (nedge < 0) nedge = 0;
  for (int i = tid; i < MAXNB; i += 512) hist[i] = 0;
  __syncthreads();
  #pragma unroll
  for (int k = 0; k < BCH_BIND/512; ++k) {
    int e = e0 + k*512 + tid;
    if (e < E) atomicAdd(&hist[dst[e] >> 8], 1);
  }
  __syncthreads();
  {
    int base = tid * 2;
    int v0 = hist[base], v1 = hist[base+1];
    int s = v0+v1;
    tmp[tid] = s;
    __syncthreads();
    for (int off=1; off<512; off<<=1){
      int x = (tid >= off) ? tmp[tid-off] : 0;
      __syncthreads();
      tmp[tid] += x;
      __syncthreads();
    }
    int run = tmp[tid] - s;
    scanb[base] = run; run += v0;
    scanb[base+1] = run;
  }
  __syncthreads();
  for (int i = tid; i < NB; i += 512) {
    int h = hist[i];
    rbase[i] = h ? atomicAdd(&bcur[i], h) : 0;
    lcur[i] = scanb[i];
  }
  __syncthreads();
  #pragma unroll
  for (int k = 0; k < BCH_BIND/512; ++k) {
    int e = e0 + k*512 + tid;
    if (e < E) {
      int d = dst[e];
      int b = d >> 8;
      int p = atomicAdd(&lcur[b], 1);
      stage[p] = ((unsigned)(d & 255) << 24) | (unsigned)src[e];
      bkt[p] = (unsigned short)b;
    }
  }
  __syncthreads();
  for (int i = tid; i < nedge; i += 512) {
    int b = (int)bkt[i];
    ebuf[rbase[b] + (i - scanb[b])] = stage[i];
  }
}

// finalize: dout_is from global deg; dst counting sort -> rp, din_is, col
__global__ __launch_bounds__(256) void finalize_dst_kernel(
    const unsigned* __restrict__ ebuf, const int* __restrict__ bbase,
    const int* __restrict__ deg,
    int* __restrict__ rp, float* __restrict__ din_is, float* __restrict__ dout_is,
    int* __restrict__ col, int N) {
  __shared__ int lcnt[256];
  __shared__ int lrp[257];
  __shared__ int lcur[256];
  __shared__ int tmp[256];
  __shared__ int colbuf[BCAP];
  int b = blockIdx.x;
  int tid = threadIdx.x;
  int node0 = b << 8;
  int node = node0 + tid;
  if (node < N) {
    int dg = deg[node]; if (dg < 1) dg = 1;
    dout_is[node] = rsqrtf((float)dg);
  }
  int e0 = bbase[b], e1 = bbase[b+1];
  int ne = e1 - e0;
  lcnt[tid] = 0;
  __syncthreads();
  for (int i = tid; i < ne; i += 256)
    atomicAdd(&lcnt[ebuf[e0+i] >> 24], 1);
  __syncthreads();
  int c = lcnt[tid];
  tmp[tid] = c;
  __syncthreads();
  for (int off=1; off<256; off<<=1){
    int x = (tid >= off) ? tmp[tid-off] : 0;
    __syncthreads();
    tmp[tid] += x;
    __syncthreads();
  }
  lrp[tid] = tmp[tid] - c;
  lcur[tid] = tmp[tid] - c;
  if (tid == 255) lrp[256] = tmp[255];
  __syncthreads();
  if (node < N) {
    rp[node] = e0 + lrp[tid];
    int cc = c < 1 ? 1 : c;
    din_is[node] = rsqrtf((float)cc);
  }
  if (ne <= BCAP) {
    for (int i = tid; i < ne; i += 256) {
      unsigned ed = ebuf[e0+i];
      int p = atomicAdd(&lcur[ed >> 24], 1);
      colbuf[p] = (int)(ed & 0xFFFFFFu);
    }
    __syncthreads();
    for (int i = tid; i < ne; i += 256) col[e0+i] = colbuf[i];
  } else {
    for (int i = tid; i < ne; i += 256) {
      unsigned ed = ebuf[e0+i];
      int p = atomicAdd(&lcur[ed >> 24], 1);
      col[e0+p] = (int)(ed & 0xFFFFFFu);
    }
  }
}

// ---------------- all W -> transposed bf16 hi/lo in ONE launch ----------------
__global__ void wt_all_kernel(const float* __restrict__ W1, const float* __restrict__ W2,
                              const float* __restrict__ W3,
                              unsigned short* __restrict__ Wt1hi, unsigned short* __restrict__ Wt1lo,
                              unsigned short* __restrict__ Wt2hi, unsigned short* __restrict__ Wt2lo,
                              unsigned short* __restrict__ Wt3hi, unsigned short* __restrict__ Wt3lo) {
  int idx = blockIdx.x * blockDim.x + threadIdx.x;
  const float* W; unsigned short *Hi, *Lo; int nreal, local;
  if (idx < 16384)      { W = W1; Hi = Wt1hi; Lo = Wt1lo; nreal = 128; local = idx; }
  else if (idx < 32768) { W = W2; Hi = Wt2hi; Lo = Wt2lo; nreal = 128; local = idx - 16384; }
  else if (idx < 38912) { W = W3; Hi = Wt3hi; Lo = Wt3lo; nreal = 40;  local = idx - 32768; }
  else return;
  int n = local >> 7;
  int k = local & 127;
  float v = (n < nreal) ? W[k * nreal + n] : 0.f;
  unsigned short h = f2bf(v);
  Hi[local] = h;
  Lo[local] = f2bf(v - bf2f(h));
}

// ---------------- cast x (fp32 row) -> bf16 row pre-scaled by dout_is ----------------
__global__ void cast_scale_kernel(const float* __restrict__ x, const float* __restrict__ dout_is,
                                  unsigned* __restrict__ xb2, int n4) {
  int i = blockIdx.x * blockDim.x + threadIdx.x;
  if (i >= n4) return;
  float4 v = ((const float4*)x)[i];
  int row = i >> 5;
  float sc = dout_is[row];
  unsigned lo = (unsigned)f2bf(v.x * sc) | ((unsigned)f2bf(v.y * sc) << 16);
  unsigned hi = (unsigned)f2bf(v.z * sc) | ((unsigned)f2bf(v.w * sc) << 16);
  ((uint2*)xb2)[i] = make_uint2(lo, hi);
}

__device__ inline void acc8(float* a, uint4 v) {
  float2 f;
  f = bfp2f2(v.x); a[0]+=f.x; a[1]+=f.y;
  f = bfp2f2(v.y); a[2]+=f.x; a[3]+=f.y;
  f = bfp2f2(v.z); a[4]+=f.x; a[5]+=f.y;
  f = bfp2f2(v.w); a[6]+=f.x; a[7]+=f.y;
}

// ---------------- aggregation over bf16 rows (dout-prescaled), D=128, fp32 out ----------------
// persistent grid-stride waves; 16-deep gather pipeline with NAMED scalars.
// AT PATTERN CEILING: 3.5-3.8 TB/s across 4 configs -> do not touch.
__global__ __launch_bounds__(256) void agg128_kernel(
    const uint4* __restrict__ hb4,
    const int* __restrict__ rp, const int* __restrict__ col,
    const float* __restrict__ din_is, float* __restrict__ out, int N) {
  int lane = threadIdx.x & 63;
  int g = lane >> 4, j = lane & 15;
  int wid = (blockIdx.x * blockDim.x + threadIdx.x) >> 6;
  int nw = (gridDim.x * blockDim.x) >> 6;
  int ngrp = (N + 3) >> 2;
  for (int grp = wid; grp < ngrp; grp += nw) {
    int d = grp * 4 + g;
    int dc = d < N ? d : N - 1;
    int s0 = rp[dc], s1 = rp[dc + 1];
    if (d >= N) s1 = s0;
    float a[8] = {0.f,0.f,0.f,0.f,0.f,0.f,0.f,0.f};
    int e = s0;
    for (; e + 16 <= s1; e += 16) {
      int c0 = col[e],    c1 = col[e+1],  c2 = col[e+2],  c3 = col[e+3];
      int c4 = col[e+4],  c5 = col[e+5],  c6 = col[e+6],  c7 = col[e+7];
      int c8 = col[e+8],  c9 = col[e+9],  c10= col[e+10], c11= col[e+11];
      int c12= col[e+12], c13= col[e+13], c14= col[e+14], c15= col[e+15];
      uint4 v0 = hb4[(size_t)c0*16 + j];
      uint4 v1 = hb4[(size_t)c1*16 + j];
      uint4 v2 = hb4[(size_t)c2*16 + j];
      uint4 v3 = hb4[(size_t)c3*16 + j];
      uint4 v4 = hb4[(size_t)c4*16 + j];
      uint4 v5 = hb4[(size_t)c5*16 + j];
      uint4 v6 = hb4[(size_t)c6*16 + j];
      uint4 v7 = hb4[(size_t)c7*16 + j];
      uint4 v8 = hb4[(size_t)c8*16 + j];
      uint4 v9 = hb4[(size_t)c9*16 + j];
      uint4 v10= hb4[(size_t)c10*16 + j];
      uint4 v11= hb4[(size_t)c11*16 + j];
      uint4 v12= hb4[(size_t)c12*16 + j];
      uint4 v13= hb4[(size_t)c13*16 + j];
      uint4 v14= hb4[(size_t)c14*16 + j];
      uint4 v15= hb4[(size_t)c15*16 + j];
      acc8(a, v0);  acc8(a, v1);  acc8(a, v2);  acc8(a, v3);
      acc8(a, v4);  acc8(a, v5);  acc8(a, v6);  acc8(a, v7);
      acc8(a, v8);  acc8(a, v9);  acc8(a, v10); acc8(a, v11);
      acc8(a, v12); acc8(a, v13); acc8(a, v14); acc8(a, v15);
    }
    for (; e + 8 <= s1; e += 8) {
      int c0 = col[e],   c1 = col[e+1], c2 = col[e+2], c3 = col[e+3];
      int c4 = col[e+4], c5 = col[e+5], c6 = col[e+6], c7 = col[e+7];
      uint4 v0 = hb4[(size_t)c0*16 + j];
      uint4 v1 = hb4[(size_t)c1*16 + j];
      uint4 v2 = hb4[(size_t)c2*16 + j];
      uint4 v3 = hb4[(size_t)c3*16 + j];
      uint4 v4 = hb4[(size_t)c4*16 + j];
      uint4 v5 = hb4[(size_t)c5*16 + j];
      uint4 v6 = hb4[(size_t)c6*16 + j];
      uint4 v7 = hb4[(size_t)c7*16 + j];
      acc8(a, v0); acc8(a, v1); acc8(a, v2); acc8(a, v3);
      acc8(a, v4); acc8(a, v5); acc8(a, v6); acc8(a, v7);
    }
    for (; e + 4 <= s1; e += 4) {
      int c0 = col[e], c1 = col[e+1], c2 = col[e+2], c3 = col[e+3];
      uint4 v0 = hb4[(size_t)c0*16 + j];
      uint4 v1 = hb4[(size_t)c1*16 + j];
      uint4 v2 = hb4[(size_t)c2*16 + j];
      uint4 v3 = hb4[(size_t)c3*16 + j];
      acc8(a, v0); acc8(a, v1); acc8(a, v2); acc8(a, v3);
    }
    for (; e < s1; ++e) acc8(a, hb4[(size_t)col[e]*16 + j]);
    if (d < N) {
      float di = din_is[d];
      float4* ob = (float4*)out + (size_t)d*32 + 2*j;
      ob[0] = make_float4(a[0]*di, a[1]*di, a[2]*di, a[3]*di);
      ob[1] = make_float4(a[4]*di, a[5]*di, a[6]*di, a[7]*di);
    }
  }
}

// ---------------- MFMA GEMM 128->128 + fused BN stats ----------------
// 512-thread blocks (8 waves share ONE 64 KB LDS B-copy; 2 blocks/CU).
// Non-persistent: block = one 128-row tile (persistent variant regressed r9).
// XOR swizzle: slot = c ^ (row&7) -> conflict-free ds_read_b128.
__global__ __launch_bounds__(512) void gemm128_stats_kernel(
    const float* __restrict__ A,
    const uint4* __restrict__ Bhi, const uint4* __restrict__ Blo,
    const float* __restrict__ bias, float* __restrict__ Out,
    float* __restrict__ colS, float* __restrict__ colSS, int N) {
  __shared__ uint4 Bh[2048];    // 32 KB
  __shared__ uint4 Bl[2048];    // 32 KB
  __shared__ float sblk[8][128];
  __shared__ float ssblk[8][128];
  int tid = threadIdx.x;
  // stage B: linear uint4 idx = row*16 + c  ->  LDS slot row*16 + (c ^ (row&7))
  for (int i = tid; i < 2048; i += 512) {
    int row = i >> 4, c = i & 15;
    int s = (row << 4) | (c ^ (row & 7));
    Bh[s] = Bhi[i];
    Bl[s] = Blo[i];
  }
  int wave = tid >> 6;
  int lane = tid & 63;
  int quad = lane >> 4, j = lane & 15;
  int j16 = j << 4;
  int jx = j & 7;
  float st[8], sst[8], bs[8];
  #pragma unroll
  for (int ct = 0; ct < 8; ++ct) { st[ct] = 0.f; sst[ct] = 0.f; bs[ct] = bias[ct*16 + j]; }
  __syncthreads();

  int row0 = blockIdx.x * 128 + wave * 16;
  int row = row0 + j;
  int rl = row < N ? row : N - 1;
  float4 cur[8];
  #pragma unroll
  for (int kc = 0; kc < 4; ++kc) {
    const float* ap = A + (size_t)rl*128 + kc*32 + quad*8;
    cur[2*kc]   = *(const float4*)(ap);
    cur[2*kc+1] = *(const float4*)(ap + 4);
  }
  floatx4 acc[8];
  #pragma unroll
  for (int ct = 0; ct < 8; ++ct) acc[ct] = (floatx4){0.f,0.f,0.f,0.f};
  #pragma unroll
  for (int kc = 0; kc < 4; ++kc) {
    float4 f0 = cur[2*kc], f1 = cur[2*kc+1];
    uint4 H, L;
    hilo2(f0.x, f0.y, H.x, L.x);
    hilo2(f0.z, f0.w, H.y, L.y);
    hilo2(f1.x, f1.y, H.z, L.z);
    hilo2(f1.z, f1.w, H.w, L.w);
    bf16x8 ah = asbf(H), al = asbf(L);
    int cx = ((kc*4 + quad) ^ jx) + j16;   // swizzled slot within row + j row base
    #pragma unroll
    for (int ct = 0; ct < 8; ++ct) {
      uint4 bh = Bh[ct*256 + cx];
      uint4 bl = Bl[ct*256 + cx];
      acc[ct] = __builtin_amdgcn_mfma_f32_16x16x32_bf16(ah, asbf(bh), acc[ct], 0, 0, 0);
      acc[ct] = __builtin_amdgcn_mfma_f32_16x16x32_bf16(ah, asbf(bl), acc[ct], 0, 0, 0);
      acc[ct] = __builtin_amdgcn_mfma_f32_16x16x32_bf16(al, asbf(bh), acc[ct], 0, 0, 0);
    }
  }
  #pragma unroll
  for (int ct = 0; ct < 8; ++ct) {
    int colc = ct*16 + j;
    #pragma unroll
    for (int r = 0; r < 4; ++r) {
      int grow = row0 + quad*4 + r;
      if (grow < N) {
        float v = acc[ct][r] + bs[ct];
        Out[(size_t)grow*128 + colc] = v;
        st[ct] += v;
        sst[ct] += v*v;
      }
    }
  }
  // cross-quad reduce (lanes j, j+16, j+32, j+48 hold the same column)
  #pragma unroll
  for (int ct = 0; ct < 8; ++ct) {
    float s = st[ct], ss = sst[ct];
    s  += __shfl_xor(s, 16);  s  += __shfl_xor(s, 32);
    ss += __shfl_xor(ss, 16); ss += __shfl_xor(ss, 32);
    if (quad == 0) { sblk[wave][ct*16+j] = s; ssblk[wave][ct*16+j] = ss; }
  }
  __syncthreads();
  if (tid < 128) {
    float s  = (sblk[0][tid] + sblk[1][tid]) + (sblk[2][tid] + sblk[3][tid])
             + (sblk[4][tid] + sblk[5][tid]) + (sblk[6][tid] + sblk[7][tid]);
    float ss = (ssblk[0][tid] + ssblk[1][tid]) + (ssblk[2][tid] + ssblk[3][tid])
             + (ssblk[4][tid] + ssblk[5][tid]) + (ssblk[6][tid] + ssblk[7][tid]);
    atomicAdd(&colS[tid], s);
    atomicAdd(&colSS[tid], ss);
  }
}

// per-block BN coefficient computation (replaces the bn_finalize launch)
__device__ inline void bn_coeffs_to_lds(const float* __restrict__ colS,
                                        const float* __restrict__ colSS,
                                        const float* __restrict__ g,
                                        const float* __restrict__ be,
                                        float invN, float* cA, float* cB, int tid) {
  if (tid < 128) {
    float mu  = colS[tid] * invN;
    float var = colSS[tid] * invN - mu*mu;
    if (var < 0.f) var = 0.f;
    float rs = rsqrtf(var + 1e-5f);
    float a = g[tid] * rs;
    cA[tid] = a;
    cB[tid] = be[tid] - mu*a;
  }
}

// ---------------- FUSED: BN-apply + ReLU + MFMA GEMM (128 -> 40, bf16 out) ----------------
// Output rows PADDED to 64 shorts (128 B): one cache line per row for layer-3 gather.
__global__ __launch_bounds__(256) void bn_gemm40_kernel(
    const float* __restrict__ A,
    const float* __restrict__ colS, const float* __restrict__ colSS,
    const float* __restrict__ g, const float* __restrict__ be,
    const uint4* __restrict__ Bhi, const uint4* __restrict__ Blo,
    const float* __restrict__ rowscale,
    unsigned short* __restrict__ OutB, float invN, int N) {
  __shared__ float cA[128], cB[128];
  int tid = threadIdx.x;
  bn_coeffs_to_lds(colS, colSS, g, be, invN, cA, cB, tid);
  __syncthreads();
  int wave = tid >> 6;
  int lane = tid & 63;
  int quad = lane >> 4, j = lane & 15;
  int row0 = blockIdx.x * 64 + wave * 16;
  int row = row0 + j;
  int rl = row < N ? row : N - 1;
  floatx4 acc[3];
  #pragma unroll
  for (int ct = 0; ct < 3; ++ct) acc[ct] = (floatx4){0.f,0.f,0.f,0.f};
  #pragma unroll
  for (int kc = 0; kc < 4; ++kc) {
    const float* ap = A + (size_t)rl*128 + kc*32 + quad*8;
    float4 f0 = *(const float4*)(ap);
    float4 f1 = *(const float4*)(ap + 4);
    const float* ca = cA + kc*32 + quad*8;
    const float* cb = cB + kc*32 + quad*8;
    float4 a0 = *(const float4*)(ca), a1 = *(const float4*)(ca + 4);
    float4 b0 = *(const float4*)(cb), b1 = *(const float4*)(cb + 4);
    float y0 = fmaxf(f0.x*a0.x + b0.x, 0.f);
    float y1 = fmaxf(f0.y*a0.y + b0.y, 0.f);
    float y2 = fmaxf(f0.z*a0.z + b0.z, 0.f);
    float y3 = fmaxf(f0.w*a0.w + b0.w, 0.f);
    float y4 = fmaxf(f1.x*a1.x + b1.x, 0.f);
    float y5 = fmaxf(f1.y*a1.y + b1.y, 0.f);
    float y6 = fmaxf(f1.z*a1.z + b1.z, 0.f);
    float y7 = fmaxf(f1.w*a1.w + b1.w, 0.f);
    uint4 H, L;
    hilo2(y0, y1, H.x, L.x);
    hilo2(y2, y3, H.y, L.y);
    hilo2(y4, y5, H.z, L.z);
    hilo2(y6, y7, H.w, L.w);
    bf16x8 ah = asbf(H), al = asbf(L);
    #pragma unroll
    for (int ct = 0; ct < 3; ++ct) {
      int nr = ct*16 + j;
      uint4 bh = Bhi[nr*16 + kc*4 + quad];
      uint4 bl = Blo[nr*16 + kc*4 + quad];
      acc[ct] = __builtin_amdgcn_mfma_f32_16x16x32_bf16(ah, asbf(bh), acc[ct], 0, 0, 0);
      acc[ct] = __builtin_amdgcn_mfma_f32_16x16x32_bf16(ah, asbf(bl), acc[ct], 0, 0, 0);
      acc[ct] = __builtin_amdgcn_mfma_f32_16x16x32_bf16(al, asbf(bh), acc[ct], 0, 0, 0);
    }
  }
  #pragma unroll
  for (int r = 0; r < 4; ++r) {
    int grow = row0 + quad*4 + r;
    if (grow < N) {
      float sc = rowscale[grow];
      #pragma unroll
      for (int ct = 0; ct < 3; ++ct) {
        int colc = ct*16 + j;
        if (colc < 40) OutB[(size_t)grow*64 + colc] = f2bf(acc[ct][r] * sc);
      }
    }
  }
}

// bf16 out, pre-scaled by dout_is (feeds the layer-2 gather).
__global__ __launch_bounds__(256) void bn_apply_bf16_kernel(
    const float* __restrict__ raw,
    const float* __restrict__ colS, const float* __restrict__ colSS,
    const float* __restrict__ g, const float* __restrict__ be,
    const float* __restrict__ dout_is,
    unsigned* __restrict__ outb, float invN, int n4) {
  __shared__ float cA[128], cB[128];
  int tid = threadIdx.x;
  bn_coeffs_to_lds(colS, colSS, g, be, invN, cA, cB, tid);
  __syncthreads();
  int i = blockIdx.x * blockDim.x + tid;
  if (i >= n4) return;
  float4 v = ((const float4*)raw)[i];
  int c4 = i & 31;
  int row = i >> 5;
  float sc = dout_is[row];
  float4 a = *(const float4*)&cA[c4*4];
  float4 b = *(const float4*)&cB[c4*4];
  float x0 = fmaxf(v.x*a.x + b.x, 0.f) * sc;
  float x1 = fmaxf(v.y*a.y + b.y, 0.f) * sc;
  float x2 = fmaxf(v.z*a.z + b.z, 0.f) * sc;
  float x3 = fmaxf(v.w*a.w + b.w, 0.f) * sc;
  unsigned lo = (unsigned)f2bf(x0) | ((unsigned)f2bf(x1) << 16);
  unsigned hi = (unsigned)f2bf(x2) | ((unsigned)f2bf(x3) << 16);
  ((uint2*)outb)[i] = make_uint2(lo, hi);
}

// ---------------- layer 3: aggregate 40-dim bf16 (pre-scaled) + bias + log_softmax ----------------
// persistent grid-stride waves; 16-deep NAMED-scalar pipeline (VGPR 56; the
// 32-deep variant collapsed to VGPR 44 and serialized: 93us, r9).
// tb rows 128 B aligned: one line per gathered row.
__global__ __launch_bounds__(256) void final_kernel(
    const unsigned* __restrict__ tb,
    const int* __restrict__ rp, const int* __restrict__ col,
    const float* __restrict__ din_is, const float* __restrict__ b3,
    float* __restrict__ out, int N) {
  int g = (threadIdx.x >> 5) & 1;
  int j = threadIdx.x & 31;
  bool act = (j < 20);
  int wid = (blockIdx.x * blockDim.x + threadIdx.x) >> 6;
  int nw = (gridDim.x * blockDim.x) >> 6;
  int ngrp = (N + 1) >> 1;
  for (int grp = wid; grp < ngrp; grp += nw) {
    int d = grp * 2 + g;
    int dc = d < N ? d : N - 1;
    int s0 = rp[dc], s1 = rp[dc + 1];
    if (d >= N) s1 = s0;
    float a0 = 0.f, a1 = 0.f;
    int e = s0;
    for (; e + 16 <= s1; e += 16) {
      int c0 = col[e],    c1 = col[e+1],  c2 = col[e+2],  c3 = col[e+3];
      int c4 = col[e+4],  c5 = col[e+5],  c6 = col[e+6],  c7 = col[e+7];
      int c8 = col[e+8],  c9 = col[e+9],  c10= col[e+10], c11= col[e+11];
      int c12= col[e+12], c13= col[e+13], c14= col[e+14], c15= col[e+15];
      unsigned u0 = act ? tb[(size_t)c0*32 + j] : 0u;
      unsigned u1 = act ? tb[(size_t)c1*32 + j] : 0u;
      unsigned u2 = act ? tb[(size_t)c2*32 + j] : 0u;
      unsigned u3 = act ? tb[(size_t)c3*32 + j] : 0u;
      unsigned u4 = act ? tb[(size_t)c4*32 + j] : 0u;
      unsigned u5 = act ? tb[(size_t)c5*32 + j] : 0u;
      unsigned u6 = act ? tb[(size_t)c6*32 + j] : 0u;
      unsigned u7 = act ? tb[(size_t)c7*32 + j] : 0u;
      unsigned u8 = act ? tb[(size_t)c8*32 + j] : 0u;
      unsigned u9 = act ? tb[(size_t)c9*32 + j] : 0u;
      unsigned u10= act ? tb[(size_t)c10*32 + j] : 0u;
      unsigned u11= act ? tb[(size_t)c11*32 + j] : 0u;
      unsigned u12= act ? tb[(size_t)c12*32 + j] : 0u;
      unsigned u13= act ? tb[(size_t)c13*32 + j] : 0u;
      unsigned u14= act ? tb[(size_t)c14*32 + j] : 0u;
      unsigned u15= act ? tb[(size_t)c15*32 + j] : 0u;
      float2 f0 = bfp2f2(u0),  f1 = bfp2f2(u1),  f2 = bfp2f2(u2),  f3 = bfp2f2(u3);
      float2 f4 = bfp2f2(u4),  f5 = bfp2f2(u5),  f6 = bfp2f2(u6),  f7 = bfp2f2(u7);
      float2 f8 = bfp2f2(u8),  f9 = bfp2f2(u9),  f10= bfp2f2(u10), f11= bfp2f2(u11);
      float2 f12= bfp2f2(u12), f13= bfp2f2(u13), f14= bfp2f2(u14), f15= bfp2f2(u15);
      a0 += (((f0.x + f1.x) + (f2.x + f3.x)) + ((f4.x + f5.x) + (f6.x + f7.x)))
          + (((f8.x + f9.x) + (f10.x+ f11.x)) + ((f12.x+ f13.x) + (f14.x+ f15.x)));
      a1 += (((f0.y + f1.y) + (f2.y + f3.y)) + ((f4.y + f5.y) + (f6.y + f7.y)))
          + (((f8.y + f9.y) + (f10.y+ f11.y)) + ((f12.y+ f13.y) + (f14.y+ f15.y)));
    }
    for (; e + 4 <= s1; e += 4) {
      int c0 = col[e], c1 = col[e+1], c2 = col[e+2], c3 = col[e+3];
      unsigned u0 = act ? tb[(size_t)c0*32 + j] : 0u;
      unsigned u1 = act ? tb[(size_t)c1*32 + j] : 0u;
      unsigned u2 = act ? tb[(size_t)c2*32 + j] : 0u;
      unsigned u3 = act ? tb[(size_t)c3*32 + j] : 0u;
      float2 f0 = bfp2f2(u0), f1 = bfp2f2(u1), f2 = bfp2f2(u2), f3 = bfp2f2(u3);
      a0 += (f0.x + f1.x) + (f2.x + f3.x);
      a1 += (f0.y + f1.y) + (f2.y + f3.y);
    }
    for (; e < s1; ++e) {
      unsigned u = act ? tb[(size_t)col[e]*32 + j] : 0u;
      float2 f = bfp2f2(u);
      a0 += f.x; a1 += f.y;
    }
    float di = din_is[dc];
    float z0 = act ? di*a0 + b3[2*j]   : -1e30f;
    float z1 = act ? di*a1 + b3[2*j+1] : -1e30f;
    float m = fmaxf(z0, z1);
    #pragma unroll
    for (int off=16; off>0; off>>=1) m = fmaxf(m, __shfl_xor(m, off, 32));
    float s = act ? (expf(z0-m) + expf(z1-m)) : 0.f;
    #pragma unroll
    for (int off=16; off>0; off>>=1) s += __shfl_xor(s, off, 32);
    float lg = logf(s);
    if (act && d < N) {
      float2 o = make_float2(z0 - m - lg, z1 - m - lg);
      ((float2*)(out + (size_t)d*40))[j] = o;
    }
  }
}

// ---------------- host ----------------
extern "C" void kernel_launch(void* const* d_in, const int* in_sizes, int n_in,
                              void* d_out, int out_size, void* d_ws, size_t ws_size,
                              hipStream_t stream) {
  const float* x   = (const float*)d_in[0];
  const int*   src = (const int*)d_in[1];
  const int*   dst = (const int*)d_in[2];
  const float* W1  = (const float*)d_in[3];
  const float* b1  = (const float*)d_in[4];
  const float* g1  = (const float*)d_in[5];
  const float* be1 = (const float*)d_in[6];
  const float* W2  = (const float*)d_in[7];
  const float* b2  = (const float*)d_in[8];
  const float* g2  = (const float*)d_in[9];
  const float* be2 = (const float*)d_in[10];
  const float* W3  = (const float*)d_in[11];
  const float* b3  = (const float*)d_in[12];
  const int E = in_sizes[1];
  const int D = in_sizes[4];     // 128
  const int N = in_sizes[0] / D; // 100000
  float* out = (float*)d_out;

  char* p = (char*)d_ws;
  auto alloc = [&](size_t bytes) { char* q = p; p += (bytes + 255) & ~(size_t)255; return q; };
  int* rp        = (int*)alloc((size_t)(N+1)*4);
  float* din_is  = (float*)alloc((size_t)N*4);
  float* dout_is = (float*)alloc((size_t)N*4);
  // zeroed region: stats (4*128 floats) + bcnt (MAXNB) + deg (N), contiguous -> ONE memset
  float* stats   = (float*)alloc((size_t)4*128*4);
  int* bcnt      = (int*)alloc((size_t)MAXNB*4);
  int* deg       = (int*)alloc((size_t)N*4);
  size_t zero_span = (size_t)((char*)deg + (size_t)N*4 - (char*)stats);
  int* bbase     = (int*)alloc((size_t)(MAXNB+1)*4);
  int* bcur      = (int*)alloc((size_t)MAXNB*4);
  unsigned short* Wt1hi = (unsigned short*)alloc(128*128*2);
  unsigned short* Wt1lo = (unsigned short*)alloc(128*128*2);
  unsigned short* Wt2hi = (unsigned short*)alloc(128*128*2);
  unsigned short* Wt2lo = (unsigned short*)alloc(128*128*2);
  unsigned short* Wt3hi = (unsigned short*)alloc(48*128*2);
  unsigned short* Wt3lo = (unsigned short*)alloc(48*128*2);
  int*   col     = (int*)alloc((size_t)E*4);
  float* bufA    = (float*)alloc((size_t)N*D*4);      // GEMM output (fp32)
  float* bufB    = (float*)alloc((size_t)N*D*4);      // agg output (fp32)
  unsigned* bf16buf = (unsigned*)alloc((size_t)N*D*2);  // also holds padded 128B tb rows (12.8 MB)
  // alias: CSR build finishes before bufA first writes
  unsigned* ebuf = (unsigned*)bufA;   // E uints (packed dst-low|src)

  float* colS1  = stats;
  float* colSS1 = stats + 128;
  float* colS2  = stats + 256;
  float* colSS2 = stats + 384;

  const int NB = (N + 255) >> 8;
  int cntB = (E + BCH_CNT - 1)/BCH_CNT;
  int binB = (E + BCH_BIND - 1)/BCH_BIND;

  int gemb2 = (N + 127)/128;              // 512-thread blocks, 128 rows each
  float invN = 1.0f/(float)N;

  hipMemsetAsync(stats, 0, zero_span, stream);
  wt_all_kernel<<<(38912+255)/256, 256, 0, stream>>>(W1, W2, W3, Wt1hi, Wt1lo, Wt2hi, Wt2lo, Wt3hi, Wt3lo);
  count_deg_kernel<<<cntB, 256, 0, stream>>>(src, dst, bcnt, deg, E, NB);
  scan1_kernel<<<1, 256, 0, stream>>>(bcnt, bbase, bcur, rp, NB, N, E);
  bin_dst_kernel<<<binB, 512, 0, stream>>>(src, dst, bcur, ebuf, E, NB);
  finalize_dst_kernel<<<NB, 256, 0, stream>>>(ebuf, bbase, deg, rp, din_is, dout_is, col, N);

  int aggWork = (((N + 3)/4)*64 + 255)/256;
  int aggb = aggWork < 2048 ? aggWork : 2048;   // persistent grid
  int finWork = (((N + 1)/2)*64 + 255)/256;
  int finb = finWork < 2048 ? finWork : 2048;   // persistent grid
  int gemb = (N + 63)/64;                 // 64 rows per block (bn_gemm40)
  int nel4 = (N*D)/4;

  // layer 1
  cast_scale_kernel<<<(nel4+255)/256, 256, 0, stream>>>(x, dout_is, bf16buf, nel4);
  agg128_kernel<<<aggb, 256, 0, stream>>>((const uint4*)bf16buf, rp, col, din_is, bufB, N);
  gemm128_stats_kernel<<<gemb2, 512, 0, stream>>>(bufB, (const uint4*)Wt1hi, (const uint4*)Wt1lo,
                                                  b1, bufA, colS1, colSS1, N);
  bn_apply_bf16_kernel<<<(nel4+255)/256, 256, 0, stream>>>(bufA, colS1, colSS1, g1, be1,
                                                           dout_is, bf16buf, invN, nel4);

  // layer 2
  agg128_kernel<<<aggb, 256, 0, stream>>>((const uint4*)bf16buf, rp, col, din_is, bufB, N);
  gemm128_stats_kernel<<<gemb2, 512, 0, stream>>>(bufB, (const uint4*)Wt2hi, (const uint4*)Wt2lo,
                                                  b2, bufA, colS2, colSS2, N);

  // layer 3: fused BN + GEMM to 40 dims (bf16 out, rows padded to 128 B, pre-scaled by dout),
  // then agg + softmax
  bn_gemm40_kernel<<<gemb, 256, 0, stream>>>(bufA, colS2, colSS2, g2, be2,
                                             (const uint4*)Wt3hi, (const uint4*)Wt3lo,
                                             dout_is, (unsigned short*)bf16buf, invN, N);
  final_kernel<<<finb, 256, 0, stream>>>((const unsigned*)bf16buf, rp, col, din_is, b3, out, N);
}

// Round 12
// 490.543 us; speedup vs baseline: 1.0679x; 1.0679x over previous
//
#include <hip/hip_runtime.h>
#include <math.h>

#define MAXNB 1024    // max buckets (N <= 262144 with 256 nodes/bucket)
#define BCH_CNT 2048  // edges per block in count kernel
#define BCH_BIN 2048  // edges per block in bin kernels
#define BCAP  16384   // per-bucket edge capacity in finalize (mean 4096)

typedef __attribute__((ext_vector_type(8))) __bf16 bf16x8;
typedef __attribute__((ext_vector_type(4))) float floatx4;

__device__ inline bf16x8 asbf(uint4 u) {
  union { uint4 u; bf16x8 b; } c; c.u = u; return c.b;
}

// ---------- bf16 helpers ----------
__device__ inline unsigned short f2bf(float f) {
  union { float f; unsigned u; } v; v.f = f;
  unsigned r = v.u + 0x7fffu + ((v.u >> 16) & 1u);   // round-to-nearest-even
  return (unsigned short)(r >> 16);
}
__device__ inline float bf2f(unsigned short u) {
  union { unsigned u; float f; } v; v.u = ((unsigned)u) << 16;
  return v.f;
}
__device__ inline float2 bfp2f2(unsigned u) {       // packed bf16x2 -> float2
  union { unsigned u; float f; } a, b;
  a.u = u << 16;
  b.u = u & 0xffff0000u;
  float2 r; r.x = a.f; r.y = b.f; return r;
}
// split v into hi=bf16(v), lo=bf16(v-hi); packed pair for 2 values
__device__ inline void hilo2(float v0, float v1, unsigned& h, unsigned& l) {
  unsigned short h0 = f2bf(v0); float r0 = v0 - bf2f(h0);
  unsigned short h1 = f2bf(v1); float r1 = v1 - bf2f(h1);
  h = (unsigned)h0 | ((unsigned)h1 << 16);
  l = (unsigned)f2bf(r0) | ((unsigned)f2bf(r1) << 16);
}

// ---------------- CSR build: bucketed sorts for dst (CSR) and src (out-degree) ----------------
// NOTE r11: direct global atomicAdd(&deg[src]) was 81us (random-address RMW storm,
// 51 MB writes). LDS-bucketed counting is the right structure.
__global__ __launch_bounds__(256) void count2_kernel(
    const int* __restrict__ src, const int* __restrict__ dst,
    int* __restrict__ bcnt, int* __restrict__ scnt, int E, int NB) {
  __shared__ int histd[MAXNB];
  __shared__ int hists[MAXNB];
  int tid = threadIdx.x;
  for (int i = tid; i < MAXNB; i += 256) { histd[i] = 0; hists[i] = 0; }
  __syncthreads();
  int e0 = blockIdx.x * BCH_CNT;
  #pragma unroll
  for (int k = 0; k < BCH_CNT/256; ++k) {
    int e = e0 + k*256 + tid;
    if (e < E) {
      atomicAdd(&histd[dst[e] >> 8], 1);
      atomicAdd(&hists[src[e] >> 8], 1);
    }
  }
  __syncthreads();
  for (int i = tid; i < NB; i += 256) {
    if (histd[i]) atomicAdd(&bcnt[i], histd[i]);
    if (hists[i]) atomicAdd(&scnt[i], hists[i]);
  }
}

__global__ __launch_bounds__(256) void scan2_kernel(
    const int* __restrict__ bcnt, int* __restrict__ bbase, int* __restrict__ bcur,
    const int* __restrict__ scnt, int* __restrict__ sbase, int* __restrict__ scur,
    int* __restrict__ rp, int NB, int N, int E) {
  __shared__ int sh[256];
  int t = threadIdx.x;
  for (int pass = 0; pass < 2; ++pass) {
    const int* cnt = pass ? scnt : bcnt;
    int* base_ = pass ? sbase : bbase;
    int* cur_  = pass ? scur  : bcur;
    int base = t * 4;
    int v0 = (base+0 < NB) ? cnt[base+0] : 0;
    int v1 = (base+1 < NB) ? cnt[base+1] : 0;
    int v2 = (base+2 < NB) ? cnt[base+2] : 0;
    int v3 = (base+3 < NB) ? cnt[base+3] : 0;
    int s = v0+v1+v2+v3;
    sh[t] = s;
    __syncthreads();
    for (int off=1; off<256; off<<=1){
      int x = (t >= off) ? sh[t-off] : 0;
      __syncthreads();
      sh[t] += x;
      __syncthreads();
    }
    int run = sh[t] - s;
    if (base+0 <= NB) { base_[base+0] = run; if (base+0 < NB) cur_[base+0] = run; } run += v0;
    if (base+1 <= NB) { base_[base+1] = run; if (base+1 < NB) cur_[base+1] = run; } run += v1;
    if (base+2 <= NB) { base_[base+2] = run; if (base+2 < NB) cur_[base+2] = run; } run += v2;
    if (base+3 <= NB) { base_[base+3] = run; if (base+3 < NB) cur_[base+3] = run; }
    __syncthreads();
  }
  if (t == 0) rp[N] = E;
}

// MERGED C3: bin by dst bucket AND src bucket in one kernel.
// r12 fix: dst bucket id recorded in ushort LDS at scatter time -> the dst
// writeback is 2 LDS reads + 1 store (the old 10-iteration LDS binary search
// chain was the dominant serial cost: 67us @ 0.5 TB/s). The src side always
// derived its bucket directly from the value (no search) and is unchanged.
__global__ __launch_bounds__(256) void bin_both_kernel(
    const int* __restrict__ src, const int* __restrict__ dst,
    int* __restrict__ bcur, unsigned* __restrict__ ebuf,
    int* __restrict__ scur, unsigned* __restrict__ sbuf, int E, int NB) {
  __shared__ int histd[MAXNB];
  __shared__ int scand[MAXNB];
  __shared__ int rbased[MAXNB];
  __shared__ int lcurd[MAXNB];
  __shared__ int hists[MAXNB];
  __shared__ int scans_[MAXNB];
  __shared__ int rbases[MAXNB];
  __shared__ int lcurs[MAXNB];
  __shared__ int tmp[256];
  __shared__ unsigned staged[BCH_BIN];
  __shared__ unsigned stages[BCH_BIN];
  __shared__ unsigned short bktd[BCH_BIN];
  int tid = threadIdx.x;
  int e0 = blockIdx.x * BCH_BIN;
  int nedge = E - e0; if (nedge > BCH_BIN) nedge = BCH_BIN; if (nedge < 0) nedge = 0;
  for (int i = tid; i < MAXNB; i += 256) { histd[i] = 0; hists[i] = 0; }
  __syncthreads();
  #pragma unroll
  for (int k = 0; k < BCH_BIN/256; ++k) {
    int e = e0 + k*256 + tid;
    if (e < E) {
      atomicAdd(&histd[dst[e] >> 8], 1);
      atomicAdd(&hists[src[e] >> 8], 1);
    }
  }
  __syncthreads();
  for (int pass = 0; pass < 2; ++pass) {
    int* hist  = pass ? hists  : histd;
    int* scanb = pass ? scans_ : scand;
    int base = tid * 4;
    int v0 = hist[base+0], v1 = hist[base+1], v2 = hist[base+2], v3 = hist[base+3];
    int s = v0+v1+v2+v3;
    tmp[tid] = s;
    __syncthreads();
    for (int off=1; off<256; off<<=1){
      int x = (tid >= off) ? tmp[tid-off] : 0;
      __syncthreads();
      tmp[tid] += x;
      __syncthreads();
    }
    int run = tmp[tid] - s;
    scanb[base+0] = run; run += v0;
    scanb[base+1] = run; run += v1;
    scanb[base+2] = run; run += v2;
    scanb[base+3] = run;
    __syncthreads();
  }
  for (int i = tid; i < NB; i += 256) {
    int hd = histd[i];
    rbased[i] = hd ? atomicAdd(&bcur[i], hd) : 0;
    lcurd[i] = scand[i];
    int hs = hists[i];
    rbases[i] = hs ? atomicAdd(&scur[i], hs) : 0;
    lcurs[i] = scans_[i];
  }
  __syncthreads();
  #pragma unroll
  for (int k = 0; k < BCH_BIN/256; ++k) {
    int e = e0 + k*256 + tid;
    if (e < E) {
      int d = dst[e];
      int s = src[e];
      int b = d >> 8;
      int pd = atomicAdd(&lcurd[b], 1);
      staged[pd] = ((unsigned)(d & 255) << 24) | (unsigned)s;
      bktd[pd] = (unsigned short)b;
      int ps = atomicAdd(&lcurs[s >> 8], 1);
      stages[ps] = (unsigned)s;
    }
  }
  __syncthreads();
  for (int i = tid; i < nedge; i += 256) {
    int b = (int)bktd[i];
    ebuf[rbased[b] + (i - scand[b])] = staged[i];
  }
  for (int i = tid; i < nedge; i += 256) {
    unsigned sv = stages[i];
    int b = (int)(sv >> 8);
    sbuf[rbases[b] + (i - scans_[b])] = sv;
  }
}

// MERGED C4: per-bucket src-degree histogram (dout_is) THEN dst counting sort
// (rp, din_is, col) in one kernel. lcnt is reused across the two phases.
__global__ __launch_bounds__(256) void finalize_both_kernel(
    const unsigned* __restrict__ ebuf, const int* __restrict__ bbase,
    const unsigned* __restrict__ sbuf, const int* __restrict__ sbase,
    int* __restrict__ rp, float* __restrict__ din_is, float* __restrict__ dout_is,
    int* __restrict__ col, int N) {
  __shared__ int lcnt[256];
  __shared__ int lrp[257];
  __shared__ int lcur[256];
  __shared__ int tmp[256];
  __shared__ int colbuf[BCAP];
  int b = blockIdx.x;
  int tid = threadIdx.x;
  int node0 = b << 8;
  int node = node0 + tid;
  // ---- src phase: out-degree histogram -> dout_is ----
  {
    int e0s = sbase[b], e1s = sbase[b+1];
    lcnt[tid] = 0;
    __syncthreads();
    for (int i = tid; i < e1s - e0s; i += 256)
      atomicAdd(&lcnt[sbuf[e0s+i] & 255u], 1);
    __syncthreads();
    if (node < N) {
      int c = lcnt[tid]; if (c < 1) c = 1;
      dout_is[node] = rsqrtf((float)c);
    }
    __syncthreads();
  }
  // ---- dst phase: counting sort -> rp, din_is, col ----
  int e0 = bbase[b], e1 = bbase[b+1];
  int ne = e1 - e0;
  lcnt[tid] = 0;
  __syncthreads();
  for (int i = tid; i < ne; i += 256)
    atomicAdd(&lcnt[ebuf[e0+i] >> 24], 1);
  __syncthreads();
  int c = lcnt[tid];
  tmp[tid] = c;
  __syncthreads();
  for (int off=1; off<256; off<<=1){
    int x = (tid >= off) ? tmp[tid-off] : 0;
    __syncthreads();
    tmp[tid] += x;
    __syncthreads();
  }
  lrp[tid] = tmp[tid] - c;
  lcur[tid] = tmp[tid] - c;
  if (tid == 255) lrp[256] = tmp[255];
  __syncthreads();
  if (node < N) {
    rp[node] = e0 + lrp[tid];
    int cc = c < 1 ? 1 : c;
    din_is[node] = rsqrtf((float)cc);
  }
  if (ne <= BCAP) {
    for (int i = tid; i < ne; i += 256) {
      unsigned ed = ebuf[e0+i];
      int p = atomicAdd(&lcur[ed >> 24], 1);
      colbuf[p] = (int)(ed & 0xFFFFFFu);
    }
    __syncthreads();
    for (int i = tid; i < ne; i += 256) col[e0+i] = colbuf[i];
  } else {
    for (int i = tid; i < ne; i += 256) {
      unsigned ed = ebuf[e0+i];
      int p = atomicAdd(&lcur[ed >> 24], 1);
      col[e0+p] = (int)(ed & 0xFFFFFFu);
    }
  }
}

// ---------------- all W -> transposed bf16 hi/lo in ONE launch ----------------
__global__ void wt_all_kernel(const float* __restrict__ W1, const float* __restrict__ W2,
                              const float* __restrict__ W3,
                              unsigned short* __restrict__ Wt1hi, unsigned short* __restrict__ Wt1lo,
                              unsigned short* __restrict__ Wt2hi, unsigned short* __restrict__ Wt2lo,
                              unsigned short* __restrict__ Wt3hi, unsigned short* __restrict__ Wt3lo) {
  int idx = blockIdx.x * blockDim.x + threadIdx.x;
  const float* W; unsigned short *Hi, *Lo; int nreal, local;
  if (idx < 16384)      { W = W1; Hi = Wt1hi; Lo = Wt1lo; nreal = 128; local = idx; }
  else if (idx < 32768) { W = W2; Hi = Wt2hi; Lo = Wt2lo; nreal = 128; local = idx - 16384; }
  else if (idx < 38912) { W = W3; Hi = Wt3hi; Lo = Wt3lo; nreal = 40;  local = idx - 32768; }
  else return;
  int n = local >> 7;
  int k = local & 127;
  float v = (n < nreal) ? W[k * nreal + n] : 0.f;
  unsigned short h = f2bf(v);
  Hi[local] = h;
  Lo[local] = f2bf(v - bf2f(h));
}

// ---------------- cast x (fp32 row) -> bf16 row pre-scaled by dout_is ----------------
__global__ void cast_scale_kernel(const float* __restrict__ x, const float* __restrict__ dout_is,
                                  unsigned* __restrict__ xb2, int n4) {
  int i = blockIdx.x * blockDim.x + threadIdx.x;
  if (i >= n4) return;
  float4 v = ((const float4*)x)[i];
  int row = i >> 5;
  float sc = dout_is[row];
  unsigned lo = (unsigned)f2bf(v.x * sc) | ((unsigned)f2bf(v.y * sc) << 16);
  unsigned hi = (unsigned)f2bf(v.z * sc) | ((unsigned)f2bf(v.w * sc) << 16);
  ((uint2*)xb2)[i] = make_uint2(lo, hi);
}

__device__ inline void acc8(float* a, uint4 v) {
  float2 f;
  f = bfp2f2(v.x); a[0]+=f.x; a[1]+=f.y;
  f = bfp2f2(v.y); a[2]+=f.x; a[3]+=f.y;
  f = bfp2f2(v.z); a[4]+=f.x; a[5]+=f.y;
  f = bfp2f2(v.w); a[6]+=f.x; a[7]+=f.y;
}

// ---------------- aggregation over bf16 rows (dout-prescaled), D=128, fp32 out ----------------
// persistent grid-stride waves; 16-deep gather pipeline with NAMED scalars.
// AT PATTERN CEILING: 3.5-3.8 TB/s across 4 configs -> do not touch.
__global__ __launch_bounds__(256) void agg128_kernel(
    const uint4* __restrict__ hb4,
    const int* __restrict__ rp, const int* __restrict__ col,
    const float* __restrict__ din_is, float* __restrict__ out, int N) {
  int lane = threadIdx.x & 63;
  int g = lane >> 4, j = lane & 15;
  int wid = (blockIdx.x * blockDim.x + threadIdx.x) >> 6;
  int nw = (gridDim.x * blockDim.x) >> 6;
  int ngrp = (N + 3) >> 2;
  for (int grp = wid; grp < ngrp; grp += nw) {
    int d = grp * 4 + g;
    int dc = d < N ? d : N - 1;
    int s0 = rp[dc], s1 = rp[dc + 1];
    if (d >= N) s1 = s0;
    float a[8] = {0.f,0.f,0.f,0.f,0.f,0.f,0.f,0.f};
    int e = s0;
    for (; e + 16 <= s1; e += 16) {
      int c0 = col[e],    c1 = col[e+1],  c2 = col[e+2],  c3 = col[e+3];
      int c4 = col[e+4],  c5 = col[e+5],  c6 = col[e+6],  c7 = col[e+7];
      int c8 = col[e+8],  c9 = col[e+9],  c10= col[e+10], c11= col[e+11];
      int c12= col[e+12], c13= col[e+13], c14= col[e+14], c15= col[e+15];
      uint4 v0 = hb4[(size_t)c0*16 + j];
      uint4 v1 = hb4[(size_t)c1*16 + j];
      uint4 v2 = hb4[(size_t)c2*16 + j];
      uint4 v3 = hb4[(size_t)c3*16 + j];
      uint4 v4 = hb4[(size_t)c4*16 + j];
      uint4 v5 = hb4[(size_t)c5*16 + j];
      uint4 v6 = hb4[(size_t)c6*16 + j];
      uint4 v7 = hb4[(size_t)c7*16 + j];
      uint4 v8 = hb4[(size_t)c8*16 + j];
      uint4 v9 = hb4[(size_t)c9*16 + j];
      uint4 v10= hb4[(size_t)c10*16 + j];
      uint4 v11= hb4[(size_t)c11*16 + j];
      uint4 v12= hb4[(size_t)c12*16 + j];
      uint4 v13= hb4[(size_t)c13*16 + j];
      uint4 v14= hb4[(size_t)c14*16 + j];
      uint4 v15= hb4[(size_t)c15*16 + j];
      acc8(a, v0);  acc8(a, v1);  acc8(a, v2);  acc8(a, v3);
      acc8(a, v4);  acc8(a, v5);  acc8(a, v6);  acc8(a, v7);
      acc8(a, v8);  acc8(a, v9);  acc8(a, v10); acc8(a, v11);
      acc8(a, v12); acc8(a, v13); acc8(a, v14); acc8(a, v15);
    }
    for (; e + 8 <= s1; e += 8) {
      int c0 = col[e],   c1 = col[e+1], c2 = col[e+2], c3 = col[e+3];
      int c4 = col[e+4], c5 = col[e+5], c6 = col[e+6], c7 = col[e+7];
      uint4 v0 = hb4[(size_t)c0*16 + j];
      uint4 v1 = hb4[(size_t)c1*16 + j];
      uint4 v2 = hb4[(size_t)c2*16 + j];
      uint4 v3 = hb4[(size_t)c3*16 + j];
      uint4 v4 = hb4[(size_t)c4*16 + j];
      uint4 v5 = hb4[(size_t)c5*16 + j];
      uint4 v6 = hb4[(size_t)c6*16 + j];
      uint4 v7 = hb4[(size_t)c7*16 + j];
      acc8(a, v0); acc8(a, v1); acc8(a, v2); acc8(a, v3);
      acc8(a, v4); acc8(a, v5); acc8(a, v6); acc8(a, v7);
    }
    for (; e + 4 <= s1; e += 4) {
      int c0 = col[e], c1 = col[e+1], c2 = col[e+2], c3 = col[e+3];
      uint4 v0 = hb4[(size_t)c0*16 + j];
      uint4 v1 = hb4[(size_t)c1*16 + j];
      uint4 v2 = hb4[(size_t)c2*16 + j];
      uint4 v3 = hb4[(size_t)c3*16 + j];
      acc8(a, v0); acc8(a, v1); acc8(a, v2); acc8(a, v3);
    }
    for (; e < s1; ++e) acc8(a, hb4[(size_t)col[e]*16 + j]);
    if (d < N) {
      float di = din_is[d];
      float4* ob = (float4*)out + (size_t)d*32 + 2*j;
      ob[0] = make_float4(a[0]*di, a[1]*di, a[2]*di, a[3]*di);
      ob[1] = make_float4(a[4]*di, a[5]*di, a[6]*di, a[7]*di);
    }
  }
}

// ---------------- MFMA GEMM 128->128 + fused BN stats ----------------
// 512-thread blocks (8 waves share ONE 64 KB LDS B-copy; 2 blocks/CU).
// Non-persistent: block = one 128-row tile (persistent variant regressed r9).
// XOR swizzle: slot = c ^ (row&7) -> conflict-free ds_read_b128.
__global__ __launch_bounds__(512) void gemm128_stats_kernel(
    const float* __restrict__ A,
    const uint4* __restrict__ Bhi, const uint4* __restrict__ Blo,
    const float* __restrict__ bias, float* __restrict__ Out,
    float* __restrict__ colS, float* __restrict__ colSS, int N) {
  __shared__ uint4 Bh[2048];    // 32 KB
  __shared__ uint4 Bl[2048];    // 32 KB
  __shared__ float sblk[8][128];
  __shared__ float ssblk[8][128];
  int tid = threadIdx.x;
  // stage B: linear uint4 idx = row*16 + c  ->  LDS slot row*16 + (c ^ (row&7))
  for (int i = tid; i < 2048; i += 512) {
    int row = i >> 4, c = i & 15;
    int s = (row << 4) | (c ^ (row & 7));
    Bh[s] = Bhi[i];
    Bl[s] = Blo[i];
  }
  int wave = tid >> 6;
  int lane = tid & 63;
  int quad = lane >> 4, j = lane & 15;
  int j16 = j << 4;
  int jx = j & 7;
  float st[8], sst[8], bs[8];
  #pragma unroll
  for (int ct = 0; ct < 8; ++ct) { st[ct] = 0.f; sst[ct] = 0.f; bs[ct] = bias[ct*16 + j]; }
  __syncthreads();

  int row0 = blockIdx.x * 128 + wave * 16;
  int row = row0 + j;
  int rl = row < N ? row : N - 1;
  float4 cur[8];
  #pragma unroll
  for (int kc = 0; kc < 4; ++kc) {
    const float* ap = A + (size_t)rl*128 + kc*32 + quad*8;
    cur[2*kc]   = *(const float4*)(ap);
    cur[2*kc+1] = *(const float4*)(ap + 4);
  }
  floatx4 acc[8];
  #pragma unroll
  for (int ct = 0; ct < 8; ++ct) acc[ct] = (floatx4){0.f,0.f,0.f,0.f};
  #pragma unroll
  for (int kc = 0; kc < 4; ++kc) {
    float4 f0 = cur[2*kc], f1 = cur[2*kc+1];
    uint4 H, L;
    hilo2(f0.x, f0.y, H.x, L.x);
    hilo2(f0.z, f0.w, H.y, L.y);
    hilo2(f1.x, f1.y, H.z, L.z);
    hilo2(f1.z, f1.w, H.w, L.w);
    bf16x8 ah = asbf(H), al = asbf(L);
    int cx = ((kc*4 + quad) ^ jx) + j16;   // swizzled slot within row + j row base
    #pragma unroll
    for (int ct = 0; ct < 8; ++ct) {
      uint4 bh = Bh[ct*256 + cx];
      uint4 bl = Bl[ct*256 + cx];
      acc[ct] = __builtin_amdgcn_mfma_f32_16x16x32_bf16(ah, asbf(bh), acc[ct], 0, 0, 0);
      acc[ct] = __builtin_amdgcn_mfma_f32_16x16x32_bf16(ah, asbf(bl), acc[ct], 0, 0, 0);
      acc[ct] = __builtin_amdgcn_mfma_f32_16x16x32_bf16(al, asbf(bh), acc[ct], 0, 0, 0);
    }
  }
  #pragma unroll
  for (int ct = 0; ct < 8; ++ct) {
    int colc = ct*16 + j;
    #pragma unroll
    for (int r = 0; r < 4; ++r) {
      int grow = row0 + quad*4 + r;
      if (grow < N) {
        float v = acc[ct][r] + bs[ct];
        Out[(size_t)grow*128 + colc] = v;
        st[ct] += v;
        sst[ct] += v*v;
      }
    }
  }
  // cross-quad reduce (lanes j, j+16, j+32, j+48 hold the same column)
  #pragma unroll
  for (int ct = 0; ct < 8; ++ct) {
    float s = st[ct], ss = sst[ct];
    s  += __shfl_xor(s, 16);  s  += __shfl_xor(s, 32);
    ss += __shfl_xor(ss, 16); ss += __shfl_xor(ss, 32);
    if (quad == 0) { sblk[wave][ct*16+j] = s; ssblk[wave][ct*16+j] = ss; }
  }
  __syncthreads();
  if (tid < 128) {
    float s  = (sblk[0][tid] + sblk[1][tid]) + (sblk[2][tid] + sblk[3][tid])
             + (sblk[4][tid] + sblk[5][tid]) + (sblk[6][tid] + sblk[7][tid]);
    float ss = (ssblk[0][tid] + ssblk[1][tid]) + (ssblk[2][tid] + ssblk[3][tid])
             + (ssblk[4][tid] + ssblk[5][tid]) + (ssblk[6][tid] + ssblk[7][tid]);
    atomicAdd(&colS[tid], s);
    atomicAdd(&colSS[tid], ss);
  }
}

// per-block BN coefficient computation (replaces the bn_finalize launch)
__device__ inline void bn_coeffs_to_lds(const float* __restrict__ colS,
                                        const float* __restrict__ colSS,
                                        const float* __restrict__ g,
                                        const float* __restrict__ be,
                                        float invN, float* cA, float* cB, int tid) {
  if (tid < 128) {
    float mu  = colS[tid] * invN;
    float var = colSS[tid] * invN - mu*mu;
    if (var < 0.f) var = 0.f;
    float rs = rsqrtf(var + 1e-5f);
    float a = g[tid] * rs;
    cA[tid] = a;
    cB[tid] = be[tid] - mu*a;
  }
}

// ---------------- FUSED: BN-apply + ReLU + MFMA GEMM (128 -> 40, bf16 out) ----------------
// Output rows PADDED to 64 shorts (128 B): one cache line per row for layer-3 gather.
__global__ __launch_bounds__(256) void bn_gemm40_kernel(
    const float* __restrict__ A,
    const float* __restrict__ colS, const float* __restrict__ colSS,
    const float* __restrict__ g, const float* __restrict__ be,
    const uint4* __restrict__ Bhi, const uint4* __restrict__ Blo,
    const float* __restrict__ rowscale,
    unsigned short* __restrict__ OutB, float invN, int N) {
  __shared__ float cA[128], cB[128];
  int tid = threadIdx.x;
  bn_coeffs_to_lds(colS, colSS, g, be, invN, cA, cB, tid);
  __syncthreads();
  int wave = tid >> 6;
  int lane = tid & 63;
  int quad = lane >> 4, j = lane & 15;
  int row0 = blockIdx.x * 64 + wave * 16;
  int row = row0 + j;
  int rl = row < N ? row : N - 1;
  floatx4 acc[3];
  #pragma unroll
  for (int ct = 0; ct < 3; ++ct) acc[ct] = (floatx4){0.f,0.f,0.f,0.f};
  #pragma unroll
  for (int kc = 0; kc < 4; ++kc) {
    const float* ap = A + (size_t)rl*128 + kc*32 + quad*8;
    float4 f0 = *(const float4*)(ap);
    float4 f1 = *(const float4*)(ap + 4);
    const float* ca = cA + kc*32 + quad*8;
    const float* cb = cB + kc*32 + quad*8;
    float4 a0 = *(const float4*)(ca), a1 = *(const float4*)(ca + 4);
    float4 b0 = *(const float4*)(cb), b1 = *(const float4*)(cb + 4);
    float y0 = fmaxf(f0.x*a0.x + b0.x, 0.f);
    float y1 = fmaxf(f0.y*a0.y + b0.y, 0.f);
    float y2 = fmaxf(f0.z*a0.z + b0.z, 0.f);
    float y3 = fmaxf(f0.w*a0.w + b0.w, 0.f);
    float y4 = fmaxf(f1.x*a1.x + b1.x, 0.f);
    float y5 = fmaxf(f1.y*a1.y + b1.y, 0.f);
    float y6 = fmaxf(f1.z*a1.z + b1.z, 0.f);
    float y7 = fmaxf(f1.w*a1.w + b1.w, 0.f);
    uint4 H, L;
    hilo2(y0, y1, H.x, L.x);
    hilo2(y2, y3, H.y, L.y);
    hilo2(y4, y5, H.z, L.z);
    hilo2(y6, y7, H.w, L.w);
    bf16x8 ah = asbf(H), al = asbf(L);
    #pragma unroll
    for (int ct = 0; ct < 3; ++ct) {
      int nr = ct*16 + j;
      uint4 bh = Bhi[nr*16 + kc*4 + quad];
      uint4 bl = Blo[nr*16 + kc*4 + quad];
      acc[ct] = __builtin_amdgcn_mfma_f32_16x16x32_bf16(ah, asbf(bh), acc[ct], 0, 0, 0);
      acc[ct] = __builtin_amdgcn_mfma_f32_16x16x32_bf16(ah, asbf(bl), acc[ct], 0, 0, 0);
      acc[ct] = __builtin_amdgcn_mfma_f32_16x16x32_bf16(al, asbf(bh), acc[ct], 0, 0, 0);
    }
  }
  #pragma unroll
  for (int r = 0; r < 4; ++r) {
    int grow = row0 + quad*4 + r;
    if (grow < N) {
      float sc = rowscale[grow];
      #pragma unroll
      for (int ct = 0; ct < 3; ++ct) {
        int colc = ct*16 + j;
        if (colc < 40) OutB[(size_t)grow*64 + colc] = f2bf(acc[ct][r] * sc);
      }
    }
  }
}

// bf16 out, pre-scaled by dout_is (feeds the layer-2 gather).
__global__ __launch_bounds__(256) void bn_apply_bf16_kernel(
    const float* __restrict__ raw,
    const float* __restrict__ colS, const float* __restrict__ colSS,
    const float* __restrict__ g, const float* __restrict__ be,
    const float* __restrict__ dout_is,
    unsigned* __restrict__ outb, float invN, int n4) {
  __shared__ float cA[128], cB[128];
  int tid = threadIdx.x;
  bn_coeffs_to_lds(colS, colSS, g, be, invN, cA, cB, tid);
  __syncthreads();
  int i = blockIdx.x * blockDim.x + tid;
  if (i >= n4) return;
  float4 v = ((const float4*)raw)[i];
  int c4 = i & 31;
  int row = i >> 5;
  float sc = dout_is[row];
  float4 a = *(const float4*)&cA[c4*4];
  float4 b = *(const float4*)&cB[c4*4];
  float x0 = fmaxf(v.x*a.x + b.x, 0.f) * sc;
  float x1 = fmaxf(v.y*a.y + b.y, 0.f) * sc;
  float x2 = fmaxf(v.z*a.z + b.z, 0.f) * sc;
  float x3 = fmaxf(v.w*a.w + b.w, 0.f) * sc;
  unsigned lo = (unsigned)f2bf(x0) | ((unsigned)f2bf(x1) << 16);
  unsigned hi = (unsigned)f2bf(x2) | ((unsigned)f2bf(x3) << 16);
  ((uint2*)outb)[i] = make_uint2(lo, hi);
}

// ---------------- layer 3: aggregate 40-dim bf16 (pre-scaled) + bias + log_softmax ----------------
// persistent grid-stride waves; 16-deep NAMED-scalar pipeline (VGPR 56; the
// 32-deep variant collapsed to VGPR 44 and serialized: 93us, r9).
// tb rows 128 B aligned: one line per gathered row.
__global__ __launch_bounds__(256) void final_kernel(
    const unsigned* __restrict__ tb,
    const int* __restrict__ rp, const int* __restrict__ col,
    const float* __restrict__ din_is, const float* __restrict__ b3,
    float* __restrict__ out, int N) {
  int g = (threadIdx.x >> 5) & 1;
  int j = threadIdx.x & 31;
  bool act = (j < 20);
  int wid = (blockIdx.x * blockDim.x + threadIdx.x) >> 6;
  int nw = (gridDim.x * blockDim.x) >> 6;
  int ngrp = (N + 1) >> 1;
  for (int grp = wid; grp < ngrp; grp += nw) {
    int d = grp * 2 + g;
    int dc = d < N ? d : N - 1;
    int s0 = rp[dc], s1 = rp[dc + 1];
    if (d >= N) s1 = s0;
    float a0 = 0.f, a1 = 0.f;
    int e = s0;
    for (; e + 16 <= s1; e += 16) {
      int c0 = col[e],    c1 = col[e+1],  c2 = col[e+2],  c3 = col[e+3];
      int c4 = col[e+4],  c5 = col[e+5],  c6 = col[e+6],  c7 = col[e+7];
      int c8 = col[e+8],  c9 = col[e+9],  c10= col[e+10], c11= col[e+11];
      int c12= col[e+12], c13= col[e+13], c14= col[e+14], c15= col[e+15];
      unsigned u0 = act ? tb[(size_t)c0*32 + j] : 0u;
      unsigned u1 = act ? tb[(size_t)c1*32 + j] : 0u;
      unsigned u2 = act ? tb[(size_t)c2*32 + j] : 0u;
      unsigned u3 = act ? tb[(size_t)c3*32 + j] : 0u;
      unsigned u4 = act ? tb[(size_t)c4*32 + j] : 0u;
      unsigned u5 = act ? tb[(size_t)c5*32 + j] : 0u;
      unsigned u6 = act ? tb[(size_t)c6*32 + j] : 0u;
      unsigned u7 = act ? tb[(size_t)c7*32 + j] : 0u;
      unsigned u8 = act ? tb[(size_t)c8*32 + j] : 0u;
      unsigned u9 = act ? tb[(size_t)c9*32 + j] : 0u;
      unsigned u10= act ? tb[(size_t)c10*32 + j] : 0u;
      unsigned u11= act ? tb[(size_t)c11*32 + j] : 0u;
      unsigned u12= act ? tb[(size_t)c12*32 + j] : 0u;
      unsigned u13= act ? tb[(size_t)c13*32 + j] : 0u;
      unsigned u14= act ? tb[(size_t)c14*32 + j] : 0u;
      unsigned u15= act ? tb[(size_t)c15*32 + j] : 0u;
      float2 f0 = bfp2f2(u0),  f1 = bfp2f2(u1),  f2 = bfp2f2(u2),  f3 = bfp2f2(u3);
      float2 f4 = bfp2f2(u4),  f5 = bfp2f2(u5),  f6 = bfp2f2(u6),  f7 = bfp2f2(u7);
      float2 f8 = bfp2f2(u8),  f9 = bfp2f2(u9),  f10= bfp2f2(u10), f11= bfp2f2(u11);
      float2 f12= bfp2f2(u12), f13= bfp2f2(u13), f14= bfp2f2(u14), f15= bfp2f2(u15);
      a0 += (((f0.x + f1.x) + (f2.x + f3.x)) + ((f4.x + f5.x) + (f6.x + f7.x)))
          + (((f8.x + f9.x) + (f10.x+ f11.x)) + ((f12.x+ f13.x) + (f14.x+ f15.x)));
      a1 += (((f0.y + f1.y) + (f2.y + f3.y)) + ((f4.y + f5.y) + (f6.y + f7.y)))
          + (((f8.y + f9.y) + (f10.y+ f11.y)) + ((f12.y+ f13.y) + (f14.y+ f15.y)));
    }
    for (; e + 4 <= s1; e += 4) {
      int c0 = col[e], c1 = col[e+1], c2 = col[e+2], c3 = col[e+3];
      unsigned u0 = act ? tb[(size_t)c0*32 + j] : 0u;
      unsigned u1 = act ? tb[(size_t)c1*32 + j] : 0u;
      unsigned u2 = act ? tb[(size_t)c2*32 + j] : 0u;
      unsigned u3 = act ? tb[(size_t)c3*32 + j] : 0u;
      float2 f0 = bfp2f2(u0), f1 = bfp2f2(u1), f2 = bfp2f2(u2), f3 = bfp2f2(u3);
      a0 += (f0.x + f1.x) + (f2.x + f3.x);
      a1 += (f0.y + f1.y) + (f2.y + f3.y);
    }
    for (; e < s1; ++e) {
      unsigned u = act ? tb[(size_t)col[e]*32 + j] : 0u;
      float2 f = bfp2f2(u);
      a0 += f.x; a1 += f.y;
    }
    float di = din_is[dc];
    float z0 = act ? di*a0 + b3[2*j]   : -1e30f;
    float z1 = act ? di*a1 + b3[2*j+1] : -1e30f;
    float m = fmaxf(z0, z1);
    #pragma unroll
    for (int off=16; off>0; off>>=1) m = fmaxf(m, __shfl_xor(m, off, 32));
    float s = act ? (expf(z0-m) + expf(z1-m)) : 0.f;
    #pragma unroll
    for (int off=16; off>0; off>>=1) s += __shfl_xor(s, off, 32);
    float lg = logf(s);
    if (act && d < N) {
      float2 o = make_float2(z0 - m - lg, z1 - m - lg);
      ((float2*)(out + (size_t)d*40))[j] = o;
    }
  }
}

// ---------------- host ----------------
extern "C" void kernel_launch(void* const* d_in, const int* in_sizes, int n_in,
                              void* d_out, int out_size, void* d_ws, size_t ws_size,
                              hipStream_t stream) {
  const float* x   = (const float*)d_in[0];
  const int*   src = (const int*)d_in[1];
  const int*   dst = (const int*)d_in[2];
  const float* W1  = (const float*)d_in[3];
  const float* b1  = (const float*)d_in[4];
  const float* g1  = (const float*)d_in[5];
  const float* be1 = (const float*)d_in[6];
  const float* W2  = (const float*)d_in[7];
  const float* b2  = (const float*)d_in[8];
  const float* g2  = (const float*)d_in[9];
  const float* be2 = (const float*)d_in[10];
  const float* W3  = (const float*)d_in[11];
  const float* b3  = (const float*)d_in[12];
  const int E = in_sizes[1];
  const int D = in_sizes[4];     // 128
  const int N = in_sizes[0] / D; // 100000
  float* out = (float*)d_out;

  char* p = (char*)d_ws;
  auto alloc = [&](size_t bytes) { char* q = p; p += (bytes + 255) & ~(size_t)255; return q; };
  int* rp        = (int*)alloc((size_t)(N+1)*4);
  float* din_is  = (float*)alloc((size_t)N*4);
  float* dout_is = (float*)alloc((size_t)N*4);
  // zeroed region: stats (4*128 floats) + bcnt (MAXNB) + scnt (MAXNB), contiguous -> ONE memset
  float* stats   = (float*)alloc((size_t)4*128*4);
  int* bcnt      = (int*)alloc((size_t)MAXNB*4);
  int* scnt      = (int*)alloc((size_t)MAXNB*4);
  size_t zero_span = (size_t)((char*)scnt + (size_t)MAXNB*4 - (char*)stats);
  int* bbase     = (int*)alloc((size_t)(MAXNB+1)*4);
  int* bcur      = (int*)alloc((size_t)MAXNB*4);
  int* sbase     = (int*)alloc((size_t)(MAXNB+1)*4);
  int* scur      = (int*)alloc((size_t)MAXNB*4);
  unsigned short* Wt1hi = (unsigned short*)alloc(128*128*2);
  unsigned short* Wt1lo = (unsigned short*)alloc(128*128*2);
  unsigned short* Wt2hi = (unsigned short*)alloc(128*128*2);
  unsigned short* Wt2lo = (unsigned short*)alloc(128*128*2);
  unsigned short* Wt3hi = (unsigned short*)alloc(48*128*2);
  unsigned short* Wt3lo = (unsigned short*)alloc(48*128*2);
  int*   col     = (int*)alloc((size_t)E*4);
  float* bufA    = (float*)alloc((size_t)N*D*4);      // GEMM output (fp32)
  float* bufB    = (float*)alloc((size_t)N*D*4);      // agg output (fp32)
  unsigned* bf16buf = (unsigned*)alloc((size_t)N*D*2);  // also holds padded 128B tb rows (12.8 MB)
  // aliases: CSR build finishes before bufA/bufB first writes
  unsigned* ebuf = (unsigned*)bufA;   // E uints (packed dst-low|src)
  unsigned* sbuf = (unsigned*)bufB;   // E uints (src)

  float* colS1  = stats;
  float* colSS1 = stats + 128;
  float* colS2  = stats + 256;
  float* colSS2 = stats + 384;

  const int NB = (N + 255) >> 8;
  int cntB = (E + BCH_CNT - 1)/BCH_CNT;
  int binB = (E + BCH_BIN - 1)/BCH_BIN;

  int gemb2 = (N + 127)/128;              // 512-thread blocks, 128 rows each
  float invN = 1.0f/(float)N;

  hipMemsetAsync(stats, 0, zero_span, stream);
  wt_all_kernel<<<(38912+255)/256, 256, 0, stream>>>(W1, W2, W3, Wt1hi, Wt1lo, Wt2hi, Wt2lo, Wt3hi, Wt3lo);
  count2_kernel<<<cntB, 256, 0, stream>>>(src, dst, bcnt, scnt, E, NB);
  scan2_kernel<<<1, 256, 0, stream>>>(bcnt, bbase, bcur, scnt, sbase, scur, rp, NB, N, E);
  bin_both_kernel<<<binB, 256, 0, stream>>>(src, dst, bcur, ebuf, scur, sbuf, E, NB);
  finalize_both_kernel<<<NB, 256, 0, stream>>>(ebuf, bbase, sbuf, sbase, rp, din_is, dout_is, col, N);

  int aggWork = (((N + 3)/4)*64 + 255)/256;
  int aggb = aggWork < 2048 ? aggWork : 2048;   // persistent grid
  int finWork = (((N + 1)/2)*64 + 255)/256;
  int finb = finWork < 2048 ? finWork : 2048;   // persistent grid
  int gemb = (N + 63)/64;                 // 64 rows per block (bn_gemm40)
  int nel4 = (N*D)/4;

  // layer 1
  cast_scale_kernel<<<(nel4+255)/256, 256, 0, stream>>>(x, dout_is, bf16buf, nel4);
  agg128_kernel<<<aggb, 256, 0, stream>>>((const uint4*)bf16buf, rp, col, din_is, bufB, N);
  gemm128_stats_kernel<<<gemb2, 512, 0, stream>>>(bufB, (const uint4*)Wt1hi, (const uint4*)Wt1lo,
                                                  b1, bufA, colS1, colSS1, N);
  bn_apply_bf16_kernel<<<(nel4+255)/256, 256, 0, stream>>>(bufA, colS1, colSS1, g1, be1,
                                                           dout_is, bf16buf, invN, nel4);

  // layer 2
  agg128_kernel<<<aggb, 256, 0, stream>>>((const uint4*)bf16buf, rp, col, din_is, bufB, N);
  gemm128_stats_kernel<<<gemb2, 512, 0, stream>>>(bufB, (const uint4*)Wt2hi, (const uint4*)Wt2lo,
                                                  b2, bufA, colS2, colSS2, N);

  // layer 3: fused BN + GEMM to 40 dims (bf16 out, rows padded to 128 B, pre-scaled by dout),
  // then agg + softmax
  bn_gemm40_kernel<<<gemb, 256, 0, stream>>>(bufA, colS2, colSS2, g2, be2,
                                             (const uint4*)Wt3hi, (const uint4*)Wt3lo,
                                             dout_is, (unsigned short*)bf16buf, invN, N);
  final_kernel<<<finb, 256, 0, stream>>>((const unsigned*)bf16buf, rp, col, din_is, b3, out, N);
}